// Round 11
// baseline (217.886 us; speedup 1.0000x reference)
//
#include <hip/hip_runtime.h>
#include <hip/hip_bf16.h>
#include <stdint.h>

#define M_ROWS 4096
#define N_REFS 32768
#define DIM    512
#define NSPLIT 32
#define BM     128
#define CHUNK  128
#define SLICE  (N_REFS / NSPLIT)   // 1024
#define NCHUNKS (SLICE / CHUNK)    // 8
#define NKT    (DIM / 128)         // 4 K-tiles of 128 fp8 elems

typedef __attribute__((ext_vector_type(4))) int   i32x4;
typedef __attribute__((ext_vector_type(8))) int   i32x8;
typedef __attribute__((ext_vector_type(4))) float f32x4;

#define C_L2E2 2.0813689810056077f   // (log2 e)^2: exp(-sqrt(t)) == exp2(-sqrt(C*t))

// fp32 -> OCP e4m3fn, RNE, saturating. Bit-exact, no builtins.
__device__ __forceinline__ uint32_t f32_to_e4m3(float f) {
  uint32_t u = __float_as_uint(f);
  uint32_t s = (u >> 24) & 0x80u;
  float a = fabsf(f);
  if (a > 448.f) a = 448.f;                  // e4m3fn has no inf; saturate
  uint32_t b;
  if (a >= 0.015625f) {                      // normal range (>= 2^-6)
    uint32_t v = __float_as_uint(a);
    v += 0x7FFFFu + ((v >> 20) & 1u);        // RNE at mantissa bit 20
    int e = (int)(v >> 23) - 127;
    uint32_t m = (v >> 20) & 7u;
    b = (uint32_t)((e + 7) << 3) | m;
    if (b > 0x7Eu) b = 0x7Eu;                // clamp to 448
  } else {
    b = (uint32_t)(a * 512.f + 0.5f);        // subnormal grid 2^-9 (m<=8 ok)
  }
  return s | b;
}

// fp32 row -> e4m3 (packed); sum-of-squares PRE-SCALED by C_L2E2 (epilogue diet).
__global__ void prep_rows_fp8(const float* __restrict__ src, uint8_t* __restrict__ dst,
                              float* __restrict__ sq) {
  int row = blockIdx.x;
  int t = threadIdx.x;                       // 256 threads, 2 elems each
  const float2* s = (const float2*)(src + (size_t)row * DIM);
  float2 v = s[t];
  uint32_t p = f32_to_e4m3(v.x) | (f32_to_e4m3(v.y) << 8);
  ((uint16_t*)(dst + (size_t)row * DIM))[t] = (uint16_t)p;
  float ss = v.x * v.x + v.y * v.y;
  #pragma unroll
  for (int d = 32; d >= 1; d >>= 1) ss += __shfl_down(ss, d, 64);
  __shared__ float wsum[4];
  int w = t >> 6, lane = t & 63;
  if (lane == 0) wsum[w] = ss;
  __syncthreads();
  if (t == 0) sq[row] = C_L2E2 * (wsum[0] + wsum[1] + wsum[2] + wsum[3]);
}

// MX-fp8 R10 frame with A taken OUT of LDS: A (2MB fp8 total, L2-resident per
// XCD via mtile-fastest swizzle) is loaded global->VGPR per mi (2x16B, 16 live
// regs — streamed, unlike R8's 64 held regs that spilled). LDS pipe drops from
// 24 to 12 ops per wave-kt (was the largest pipe at ~55us). B keeps R10's
// verified zero-conflict staging/read swizzle. Epilogue: c-prescaled norms
// (no per-elem mul; exp2 neg is a free src modifier) + float-select fmac.
__global__ __launch_bounds__(256, 2) void ask_main(
    const uint8_t* __restrict__ xf8, const uint8_t* __restrict__ rf8,
    const float* __restrict__ cx2, const float* __restrict__ cr2,
    const int* __restrict__ y, const int* __restrict__ yref,
    float* __restrict__ totG, float* __restrict__ matchG)
{
  __shared__ unsigned char sB[16384];        // B tile only: 128 x 128B

  const int tid  = threadIdx.x;
  const int w    = tid >> 6, lane = tid & 63;
  const int wr   = w >> 1,  wc   = w & 1;
  const int l15  = lane & 15, l4 = lane >> 4;

  // XCD swizzle: grid (32 mtile x 32 nsl) = 1024 blocks; mtile fastest within
  // an XCD chunk -> per XCD: all 32 mtiles (A = 2MB, stays L2-hot) x 4 nsl.
  const int wg    = blockIdx.x;               // 0..1023
  const int c     = wg >> 3;                  // 0..127
  const int mtile = (c & 31);                 // A panel cycles fastest
  const int nsl   = (wg & 7) * 4 + (c >> 5);  // 0..31
  const int bm       = mtile * BM;
  const int colstart = nsl * SLICE;

  // B staging: srow = w*8 + lane>>3 (row in 32-row chunk), linear slot q=lane&7.
  // Source slot g chosen so reads hit slots {l4^h, (l4^h)^4} (R10 bijection):
  // e = q ^ (row&7); g = e<4 ? 2e : 2(e&3)+1.
  const int srow = w * 8 + (lane >> 3);
  const int qsl  = lane & 7;
  const int esl  = qsl ^ (srow & 7);
  const int gsl  = (esl < 4) ? (2 * esl) : (2 * (esl & 3) + 1);
  const int scol = gsl * 16;                                  // bytes

  // B fragment read slots (zero-conflict pair, measured 0 in R10)
  const int h   = l15 & 7;
  const int sl0 = (l4 ^ h) * 16;
  const int sl1 = sl0 ^ 64;
  int boff[4];
  #pragma unroll
  for (int i = 0; i < 4; ++i)
    boff[i] = (wc * 64 + i * 16 + l15) * 128;

  // A fragment global base: row = bm + wr*64 + mi*16 + l15, k = kt*128 + l4*32
  const uint8_t* aG = xf8 + (size_t)(bm + wr * 64 + l15) * DIM + l4 * 32;

  float tot[16], mat[16];
  #pragma unroll
  for (int i = 0; i < 16; ++i) { tot[i] = 0.f; mat[i] = 0.f; }

  for (int ch = 0; ch < NCHUNKS; ++ch) {
    const int colb = colstart + ch * CHUNK;
    const uint8_t* gB0 = rf8 + (size_t)(colb + srow) * DIM + scol;

    f32x4 acc[4][4];
    const f32x4 fz = {0.f, 0.f, 0.f, 0.f};
    #pragma unroll
    for (int mi = 0; mi < 4; ++mi)
      #pragma unroll
      for (int ni = 0; ni < 4; ++ni) acc[mi][ni] = fz;

    #pragma unroll
    for (int kt = 0; kt < NKT; ++kt) {
      const int dk = kt * 128;
      #pragma unroll
      for (int cc = 0; cc < 4; ++cc) {
        __builtin_amdgcn_global_load_lds(
            (const __attribute__((address_space(1))) void*)(gB0 + (size_t)cc * 32 * DIM + dk),
            (__attribute__((address_space(3))) void*)(sB + cc * 4096 + w * 1024),
            16, 0, 0);
      }
      __syncthreads();

      // B fragments from LDS (held across mi); A streamed from global (L2-hot)
      i32x8 bfr[4];
      #pragma unroll
      for (int ni = 0; ni < 4; ++ni) {
        i32x4 lo = *(const i32x4*)(sB + boff[ni] + sl0);
        i32x4 hi = *(const i32x4*)(sB + boff[ni] + sl1);
        bfr[ni] = __builtin_shufflevector(lo, hi, 0, 1, 2, 3, 4, 5, 6, 7);
      }
      #pragma unroll
      for (int mi = 0; mi < 4; ++mi) {
        i32x4 lo = *(const i32x4*)(aG + (size_t)mi * 16 * DIM + dk);
        i32x4 hi = *(const i32x4*)(aG + (size_t)mi * 16 * DIM + dk + 16);
        i32x8 afr = __builtin_shufflevector(lo, hi, 0, 1, 2, 3, 4, 5, 6, 7);
        #pragma unroll
        for (int ni = 0; ni < 4; ++ni)
          acc[mi][ni] = __builtin_amdgcn_mfma_scale_f32_16x16x128_f8f6f4(
              afr, bfr[ni], acc[mi][ni],
              0, 0,                      // cbsz=fp8(e4m3), blgp=fp8(e4m3)
              0, 0x7F7F7F7F,             // A scales = 1.0 (E8M0 127)
              0, 0x7F7F7F7F);            // B scales = 1.0
      }
      __syncthreads();
    }

    // fused epilogue: e = exp2(-sqrt(cx2 + cr2 - 2c*dot)) == exp(-dist)
    float r2c[4]; int cls[4];
    #pragma unroll
    for (int ni = 0; ni < 4; ++ni) {
      int cg = colb + wc * 64 + ni * 16 + l15;
      r2c[ni] = cr2[cg];
      cls[ni] = yref[cg];
    }
    #pragma unroll
    for (int mi = 0; mi < 4; ++mi) {
      #pragma unroll
      for (int r = 0; r < 4; ++r) {
        int row = bm + wr * 64 + mi * 16 + l4 * 4 + r;
        float xr = cx2[row];
        int   yy = y[row];
        float fsel[4];
        #pragma unroll
        for (int ni = 0; ni < 4; ++ni) fsel[ni] = (cls[ni] == yy) ? 1.0f : 0.0f;
        float tsum = 0.f, msum = 0.f;
        #pragma unroll
        for (int ni = 0; ni < 4; ++ni) {
          float t = fmaf(-2.0f * C_L2E2, acc[mi][ni][r], xr + r2c[ni]);
          t = fmaxf(t, 0.0f);
          float d = __builtin_amdgcn_sqrtf(t);
          float e = __builtin_amdgcn_exp2f(-d);       // neg = free src modifier
          tsum += e;
          msum = fmaf(e, fsel[ni], msum);
        }
        tot[mi * 4 + r] += tsum;
        mat[mi * 4 + r] += msum;
      }
    }
  }

  // reduce across the 16 lanes (l15) sharing each row, then merge globally
  #pragma unroll
  for (int i = 0; i < 16; ++i) {
    float t = tot[i], m = mat[i];
    #pragma unroll
    for (int d = 1; d <= 8; d <<= 1) {
      t += __shfl_xor(t, d, 64);
      m += __shfl_xor(m, d, 64);
    }
    if (l15 == 0) {
      int row = bm + wr * 64 + (i >> 2) * 16 + l4 * 4 + (i & 3);
      atomicAdd(&totG[row], t);
      atomicAdd(&matchG[row], m);
    }
  }
}

__global__ void finalize_loss(const float* __restrict__ totG, const float* __restrict__ matchG,
                              float* __restrict__ out) {
  __shared__ float red[256];
  int t = threadIdx.x;
  float s = 0.f;
  for (int r = t; r < M_ROWS; r += 256)
    s += logf(matchG[r] / totG[r] + 1e-6f);
  red[t] = s;
  __syncthreads();
  for (int off = 128; off >= 1; off >>= 1) {
    if (t < off) red[t] += red[t + off];
    __syncthreads();
  }
  if (t == 0) out[0] = -red[0] / (float)M_ROWS;
}

extern "C" void kernel_launch(void* const* d_in, const int* in_sizes, int n_in,
                              void* d_out, int out_size, void* d_ws, size_t ws_size,
                              hipStream_t stream) {
  const float* x    = (const float*)d_in[0];
  const float* xref = (const float*)d_in[1];
  const int*   y    = (const int*)d_in[2];
  const int*   yref = (const int*)d_in[3];
  float* out = (float*)d_out;

  uint8_t* ws = (uint8_t*)d_ws;
  uint8_t* xf8    = ws;                                 //  2 MB
  uint8_t* rf8    = ws + 2097152;                       // 16 MB
  float*   cx2    = (float*)(ws + 18874368);            // 16 KB (pre-scaled)
  float*   cr2    = (float*)(ws + 18890752);            // 128 KB (pre-scaled)
  float*   totG   = (float*)(ws + 19021824);            // 16 KB
  float*   matchG = (float*)(ws + 19038208);            // 16 KB

  hipMemsetAsync(totG, 0, 2 * M_ROWS * sizeof(float), stream);

  prep_rows_fp8<<<M_ROWS, 256, 0, stream>>>(x, xf8, cx2);
  prep_rows_fp8<<<N_REFS, 256, 0, stream>>>(xref, rf8, cr2);
  ask_main<<<dim3(M_ROWS / BM * NSPLIT), 256, 0, stream>>>(xf8, rf8, cx2, cr2, y, yref, totG, matchG);
  finalize_loss<<<1, 256, 0, stream>>>(totG, matchG, out);
}

// Round 12
// 139.312 us; speedup vs baseline: 1.5640x; 1.5640x over previous
//
#include <hip/hip_runtime.h>
#include <hip/hip_bf16.h>
#include <stdint.h>

#define M_ROWS 4096
#define N_REFS 32768
#define DIM    512
#define NSPLIT 32
#define BM     128
#define CHUNK  128
#define SLICE  (N_REFS / NSPLIT)   // 1024
#define NCHUNKS (SLICE / CHUNK)    // 8
#define NKT    (DIM / 128)         // 4 K-tiles of 128 fp8 elems
#define NSTEP  (NCHUNKS * NKT)     // 32 flattened pipeline steps

typedef __attribute__((ext_vector_type(4))) int   i32x4;
typedef __attribute__((ext_vector_type(8))) int   i32x8;
typedef __attribute__((ext_vector_type(4))) float f32x4;

#define C_L2E2 2.0813689810056077f   // (log2 e)^2: exp(-sqrt(t)) == exp2(-sqrt(C*t))

// fp32 -> OCP e4m3fn, RNE, saturating. Bit-exact, no builtins.
__device__ __forceinline__ uint32_t f32_to_e4m3(float f) {
  uint32_t u = __float_as_uint(f);
  uint32_t s = (u >> 24) & 0x80u;
  float a = fabsf(f);
  if (a > 448.f) a = 448.f;                  // e4m3fn has no inf; saturate
  uint32_t b;
  if (a >= 0.015625f) {                      // normal range (>= 2^-6)
    uint32_t v = __float_as_uint(a);
    v += 0x7FFFFu + ((v >> 20) & 1u);        // RNE at mantissa bit 20
    int e = (int)(v >> 23) - 127;
    uint32_t m = (v >> 20) & 7u;
    b = (uint32_t)((e + 7) << 3) | m;
    if (b > 0x7Eu) b = 0x7Eu;                // clamp to 448
  } else {
    b = (uint32_t)(a * 512.f + 0.5f);        // subnormal grid 2^-9 (m<=8 ok)
  }
  return s | b;
}

// fp32 row -> e4m3 (packed); sum-of-squares PRE-SCALED by C_L2E2 (epilogue diet).
__global__ void prep_rows_fp8(const float* __restrict__ src, uint8_t* __restrict__ dst,
                              float* __restrict__ sq) {
  int row = blockIdx.x;
  int t = threadIdx.x;                       // 256 threads, 2 elems each
  const float2* s = (const float2*)(src + (size_t)row * DIM);
  float2 v = s[t];
  uint32_t p = f32_to_e4m3(v.x) | (f32_to_e4m3(v.y) << 8);
  ((uint16_t*)(dst + (size_t)row * DIM))[t] = (uint16_t)p;
  float ss = v.x * v.x + v.y * v.y;
  #pragma unroll
  for (int d = 32; d >= 1; d >>= 1) ss += __shfl_down(ss, d, 64);
  __shared__ float wsum[4];
  int w = t >> 6, lane = t & 63;
  if (lane == 0) wsum[w] = ss;
  __syncthreads();
  if (t == 0) sq[row] = C_L2E2 * (wsum[0] + wsum[1] + wsum[2] + wsum[3]);
}

// R10 frame + T3-minimal double-buffer: 32 flattened (chunk,kt) steps; per
// step STAGE(g+1) is issued BEFORE reads/MFMA of step g, the single vmcnt(0)
// +raw-barrier pair comes after — stage latency hides under ds_read+MFMA,
// and under the ~1500-cyc fused epilogue at chunk boundaries (kt==3).
// Data layout, swizzles (zero-conflict, R10-measured), MFMA and epilogue
// geometry are bit-identical to R10. LDS 2x32KB=64KB -> 2 blocks/CU.
__global__ __launch_bounds__(256, 2) void ask_main(
    const uint8_t* __restrict__ xf8, const uint8_t* __restrict__ rf8,
    const float* __restrict__ cx2, const float* __restrict__ cr2,
    const int* __restrict__ y, const int* __restrict__ yref,
    float* __restrict__ totG, float* __restrict__ matchG)
{
  __shared__ unsigned char smem[2 * 32768];  // [buf][A 16KB | B 16KB]

  const int tid  = threadIdx.x;
  const int w    = tid >> 6, lane = tid & 63;
  const int wr   = w >> 1,  wc   = w & 1;
  const int l15  = lane & 15, l4 = lane >> 4;

  const int bm       = blockIdx.x * BM;
  const int colstart = blockIdx.y * SLICE;

  // staging: srow = w*8 + lane>>3 (row in 32-row chunk), linear slot q=lane&7.
  // Source slot g per the R10 bijection: e = q ^ (row&7); g = e<4 ? 2e : 2(e&3)+1.
  const int srow = w * 8 + (lane >> 3);
  const int qsl  = lane & 7;
  const int esl  = qsl ^ (srow & 7);
  const int gsl  = (esl < 4) ? (2 * esl) : (2 * (esl & 3) + 1);
  const int scol = gsl * 16;                                  // bytes
  const uint8_t* gA0 = xf8 + (size_t)(bm + srow) * DIM + scol;
  const uint8_t* gBb = rf8 + (size_t)(colstart + srow) * DIM + scol;

#define GLL(srcp, dstoff)                                                        \
  __builtin_amdgcn_global_load_lds(                                              \
      (const __attribute__((address_space(1))) void*)(srcp),                     \
      (__attribute__((address_space(3))) void*)(smem + (dstoff)), 16, 0, 0)

  // stage step gidx into buffer (gidx&1): A tile (restaged per chunk) + B tile
#define STAGE(gidx)                                                              \
  { const int ch_ = (gidx) >> 2, dk_ = ((gidx) & 3) * 128, b_ = ((gidx) & 1) * 32768; \
    const uint8_t* gA_ = gA0 + dk_;                                              \
    const uint8_t* gB_ = gBb + (size_t)ch_ * CHUNK * DIM + dk_;                  \
    _Pragma("unroll")                                                            \
    for (int cc = 0; cc < 4; ++cc) {                                             \
      GLL(gA_ + (size_t)cc * 32 * DIM, b_ + cc * 4096 + w * 1024);               \
      GLL(gB_ + (size_t)cc * 32 * DIM, b_ + 16384 + cc * 4096 + w * 1024);       \
    } }

  // fragment read slots (zero-conflict pair, measured 0 in R10)
  const int h   = l15 & 7;
  const int sl0 = (l4 ^ h) * 16;
  const int sl1 = sl0 ^ 64;
  int aoff[4], boff[4];
  #pragma unroll
  for (int i = 0; i < 4; ++i) {
    aoff[i] = (wr * 64 + i * 16 + l15) * 128;
    boff[i] = (wc * 64 + i * 16 + l15) * 128 + 16384;
  }

  // per-block row metadata, hoisted (R10 reloaded these every chunk)
  float x2v[16]; int yv[16];
  #pragma unroll
  for (int i = 0; i < 16; ++i) {
    int row = bm + wr * 64 + (i >> 2) * 16 + l4 * 4 + (i & 3);
    x2v[i] = cx2[row];
    yv[i]  = y[row];
  }

  float tot[16], mat[16];
  #pragma unroll
  for (int i = 0; i < 16; ++i) { tot[i] = 0.f; mat[i] = 0.f; }

  f32x4 acc[4][4];
  const f32x4 fz = {0.f, 0.f, 0.f, 0.f};

  // ---- prologue ----
  STAGE(0);
  asm volatile("s_waitcnt vmcnt(0)" ::: "memory");
  __builtin_amdgcn_s_barrier();

  #pragma unroll
  for (int g = 0; g < NSTEP; ++g) {
    const int kt = g & 3, ch = g >> 2;
    const int bofs = (g & 1) * 32768;

    if (g + 1 < NSTEP) { STAGE(g + 1); }

    if (kt == 0) {
      #pragma unroll
      for (int mi = 0; mi < 4; ++mi)
        #pragma unroll
        for (int ni = 0; ni < 4; ++ni) acc[mi][ni] = fz;
    }

    // B fragments from LDS (held across mi), A per mi; compiler emits lgkmcnt
    const unsigned char* pS = smem + bofs;
    i32x8 bfr[4];
    #pragma unroll
    for (int ni = 0; ni < 4; ++ni) {
      i32x4 lo = *(const i32x4*)(pS + boff[ni] + sl0);
      i32x4 hi = *(const i32x4*)(pS + boff[ni] + sl1);
      bfr[ni] = __builtin_shufflevector(lo, hi, 0, 1, 2, 3, 4, 5, 6, 7);
    }
    #pragma unroll
    for (int mi = 0; mi < 4; ++mi) {
      i32x4 lo = *(const i32x4*)(pS + aoff[mi] + sl0);
      i32x4 hi = *(const i32x4*)(pS + aoff[mi] + sl1);
      i32x8 afr = __builtin_shufflevector(lo, hi, 0, 1, 2, 3, 4, 5, 6, 7);
      #pragma unroll
      for (int ni = 0; ni < 4; ++ni)
        acc[mi][ni] = __builtin_amdgcn_mfma_scale_f32_16x16x128_f8f6f4(
            afr, bfr[ni], acc[mi][ni],
            0, 0,                      // cbsz=fp8(e4m3), blgp=fp8(e4m3)
            0, 0x7F7F7F7F,             // A scales = 1.0 (E8M0 127)
            0, 0x7F7F7F7F);            // B scales = 1.0
    }

    if (kt == 3) {
      // fused epilogue for chunk ch: e = exp2(-sqrt(cx2 + cr2 - 2c*dot));
      // sits between STAGE(g+1) issue and the vmcnt(0) drain -> hides HBM.
      const int colb = colstart + ch * CHUNK;
      float r2c[4]; int cls[4];
      #pragma unroll
      for (int ni = 0; ni < 4; ++ni) {
        int cg = colb + wc * 64 + ni * 16 + l15;
        r2c[ni] = cr2[cg];
        cls[ni] = yref[cg];
      }
      #pragma unroll
      for (int mi = 0; mi < 4; ++mi) {
        #pragma unroll
        for (int r = 0; r < 4; ++r) {
          const int gi = mi * 4 + r;
          float xr = x2v[gi];
          int   yy = yv[gi];
          float tsum = 0.f, msum = 0.f;
          #pragma unroll
          for (int ni = 0; ni < 4; ++ni) {
            float t = fmaf(-2.0f * C_L2E2, acc[mi][ni][r], xr + r2c[ni]);
            t = fmaxf(t, 0.0f);
            float d = __builtin_amdgcn_sqrtf(t);
            float e = __builtin_amdgcn_exp2f(-d);       // neg = free src modifier
            tsum += e;
            msum = fmaf(e, (cls[ni] == yy) ? 1.0f : 0.0f, msum);
          }
          tot[gi] += tsum;
          mat[gi] += msum;
        }
      }
    }

    asm volatile("s_waitcnt vmcnt(0)" ::: "memory");
    __builtin_amdgcn_s_barrier();
  }

  // reduce across the 16 lanes (l15) sharing each row, then merge globally
  #pragma unroll
  for (int i = 0; i < 16; ++i) {
    float t = tot[i], m = mat[i];
    #pragma unroll
    for (int d = 1; d <= 8; d <<= 1) {
      t += __shfl_xor(t, d, 64);
      m += __shfl_xor(m, d, 64);
    }
    if (l15 == 0) {
      int row = bm + wr * 64 + (i >> 2) * 16 + l4 * 4 + (i & 3);
      atomicAdd(&totG[row], t);
      atomicAdd(&matchG[row], m);
    }
  }
#undef GLL
#undef STAGE
}

__global__ void finalize_loss(const float* __restrict__ totG, const float* __restrict__ matchG,
                              float* __restrict__ out) {
  __shared__ float red[256];
  int t = threadIdx.x;
  float s = 0.f;
  for (int r = t; r < M_ROWS; r += 256)
    s += logf(matchG[r] / totG[r] + 1e-6f);
  red[t] = s;
  __syncthreads();
  for (int off = 128; off >= 1; off >>= 1) {
    if (t < off) red[t] += red[t + off];
    __syncthreads();
  }
  if (t == 0) out[0] = -red[0] / (float)M_ROWS;
}

extern "C" void kernel_launch(void* const* d_in, const int* in_sizes, int n_in,
                              void* d_out, int out_size, void* d_ws, size_t ws_size,
                              hipStream_t stream) {
  const float* x    = (const float*)d_in[0];
  const float* xref = (const float*)d_in[1];
  const int*   y    = (const int*)d_in[2];
  const int*   yref = (const int*)d_in[3];
  float* out = (float*)d_out;

  uint8_t* ws = (uint8_t*)d_ws;
  uint8_t* xf8    = ws;                                 //  2 MB
  uint8_t* rf8    = ws + 2097152;                       // 16 MB
  float*   cx2    = (float*)(ws + 18874368);            // 16 KB (pre-scaled)
  float*   cr2    = (float*)(ws + 18890752);            // 128 KB (pre-scaled)
  float*   totG   = (float*)(ws + 19021824);            // 16 KB
  float*   matchG = (float*)(ws + 19038208);            // 16 KB

  hipMemsetAsync(totG, 0, 2 * M_ROWS * sizeof(float), stream);

  prep_rows_fp8<<<M_ROWS, 256, 0, stream>>>(x, xf8, cx2);
  prep_rows_fp8<<<N_REFS, 256, 0, stream>>>(xref, rf8, cr2);
  ask_main<<<dim3(M_ROWS / BM, NSPLIT), 256, 0, stream>>>(xf8, rf8, cx2, cr2, y, yref, totG, matchG);
  finalize_loss<<<1, 256, 0, stream>>>(totG, matchG, out);
}